// Round 3
// baseline (360.318 us; speedup 1.0000x reference)
//
#include <hip/hip_runtime.h>

// Problem constants: B=8, H=256, W=256, C=8, K=16
// S = B*H*W = 524288 source pixels; out pixel q has 136 channels:
//   ch 0..7 = x[q][ch]
//   ch 8+j  = gauss[k][rem] * x[rem][c],  kc = q>>12 (k=kc>>3, c=kc&7),
//             rem = (q&4095)*128 + j   (j = 0..127)
// Block (k, chunk): rows q = (k*8+c)*4096 + chunk*16 + r  (c=0..7, r=0..15)
//   -> 8 CONTIGUOUS 16-row (8.7 KB) output runs, written whole (head+tail).
//   rem range needed: [chunk*2048, chunk*2048+2048) -- 2048 consecutive pixels,
//   gauss needed for this block's single k only => no recompute, no workspace.
#define S_TOTAL 524288u
#define NEG4LOG2PI (-7.3515082656373808f)

typedef float f32x4 __attribute__((ext_vector_type(4)));

// ---------------- prep: invert lower-triangular L_k, compute base_k ----------------
__global__ void prep_kernel(const float* __restrict__ scale,
                            float* __restrict__ minv,
                            float* __restrict__ base) {
    int k = threadIdx.x;
    if (k >= 16) return;
    float L[8][8], M[8][8];
    const float* Ls = scale + k * 64;
    for (int i = 0; i < 8; i++)
        for (int j = 0; j < 8; j++) { L[i][j] = Ls[i * 8 + j]; M[i][j] = 0.f; }
    for (int j = 0; j < 8; j++) {
        M[j][j] = 1.0f / L[j][j];
        for (int i = j + 1; i < 8; i++) {
            float s = 0.f;
            for (int m = j; m < i; m++) s += L[i][m] * M[m][j];
            M[i][j] = -s / L[i][i];
        }
    }
    float logdet = 0.f;
    for (int i = 0; i < 8; i++) logdet += logf(fabsf(L[i][i]));
    for (int i = 0; i < 8; i++)
        for (int j = 0; j < 8; j++) minv[k * 64 + i * 8 + j] = M[i][j];
    base[k] = -logdet + NEG4LOG2PI;
}

// ---------------- fused pass, contiguous-write decomposition ----------------
// grid = 4096 blocks: bid = chunk*16 + k  (chunk-major => the 16 k-blocks of a
// chunk are dispatch-adjacent; their shared 64-KB x-range stays L2/L3-hot).
// Per block, 2 groups of 8 rows (1024 rem pixels each):
//   stage x-range coalesced -> LDS transposed; gauss (one k) -> LDS;
//   write 8kc x 8rows full 544-B rows, contiguous f32x4 nontemporal.
template <bool INLINE_PREP>
__global__ __launch_bounds__(256) void fused_kernel(
    const float* __restrict__ x,
    const float* __restrict__ minv,
    const float* __restrict__ base,
    const float* __restrict__ mean,
    const float* __restrict__ scale,
    float* __restrict__ out)
{
    __shared__ float sXT[8][1024];  // group's x, channel-major
    __shared__ float sG[1024];      // group's gauss (this block's k)
    __shared__ float sM[64];        // k's inverse matrix
    __shared__ float sMu[8];        // k's mean
    __shared__ float sB_;           // k's base

    const unsigned t     = threadIdx.x;
    const unsigned bid   = blockIdx.x;
    const unsigned chunk = bid >> 4;    // 0..255
    const unsigned k     = bid & 15u;   // 0..15

    if (INLINE_PREP) {
        if (t == 0) {
            float L[8][8], M[8][8];
            const float* Ls = scale + k * 64u;
            for (int i = 0; i < 8; i++)
                for (int j = 0; j < 8; j++) { L[i][j] = Ls[i * 8 + j]; M[i][j] = 0.f; }
            for (int j = 0; j < 8; j++) {
                M[j][j] = 1.0f / L[j][j];
                for (int i = j + 1; i < 8; i++) {
                    float s = 0.f;
                    for (int m = j; m < i; m++) s += L[i][m] * M[m][j];
                    M[i][j] = -s / L[i][i];
                }
            }
            float logdet = 0.f;
            for (int i = 0; i < 8; i++) logdet += logf(fabsf(L[i][i]));
            for (int i = 0; i < 8; i++)
                for (int j = 0; j < 8; j++) sM[i * 8 + j] = M[i][j];
            sB_ = -logdet + NEG4LOG2PI;
        }
    } else {
        if (t < 64u) sM[t] = minv[k * 64u + t];
        if (t == 64u) sB_ = base[k];
    }
    if (t < 8u) sMu[t] = mean[k * 8u + t];
    // (first __syncthreads below covers sM/sMu/sB_ visibility)

    for (unsigned g = 0; g < 2u; ++g) {
        const unsigned px_base = chunk * 2048u + g * 1024u;  // first rem pixel

        // ---- stage + transpose: 1024 pixels = 2048 f32x4, coalesced ----
        #pragma unroll
        for (unsigned pass = 0; pass < 8u; ++pass) {
            unsigned idx = pass * 256u + t;                  // 0..2047
            f32x4 v = ((const f32x4*)x)[px_base * 2u + idx];
            unsigned p = idx >> 1, h = (idx & 1u) * 4u;
            sXT[h + 0][p] = v.x; sXT[h + 1][p] = v.y;
            sXT[h + 2][p] = v.z; sXT[h + 3][p] = v.w;
        }
        __syncthreads();

        // ---- gauss for this k: 4 pixels per thread ----
        #pragma unroll
        for (unsigned pp = 0; pp < 4u; ++pp) {
            unsigned p = pp * 256u + t;
            float d[8];
            #pragma unroll
            for (int c = 0; c < 8; c++) d[c] = sXT[c][p] - sMu[c];
            float quad = 0.f;
            #pragma unroll
            for (int i = 0; i < 8; i++) {
                float y = 0.f;
                #pragma unroll
                for (int j = 0; j <= i; j++) y = fmaf(sM[i * 8 + j], d[j], y);
                quad = fmaf(y, y, quad);
            }
            sG[p] = __expf(fmaf(-0.5f, quad, sB_));
        }
        __syncthreads();

        // ---- tail stores: 8 c x 8 rows x 32 f4 = 2048 f4, contiguous runs ----
        #pragma unroll
        for (unsigned pass = 0; pass < 8u; ++pass) {
            unsigned i  = pass * 256u + t;     // 0..2047
            unsigned c  = i >> 8;              // 0..7
            unsigned rr = (i >> 5) & 7u;       // row within group
            unsigned f2 = i & 31u;             // f4 within tail (128 floats)
            unsigned p  = rr * 128u + f2 * 4u;
            f32x4 gv = *(const f32x4*)&sG[p];
            f32x4 xc = *(const f32x4*)&sXT[c][p];
            f32x4 v  = gv * xc;
            unsigned q = (k * 8u + c) * 4096u + chunk * 16u + g * 8u + rr;
            __builtin_nontemporal_store(v, (f32x4*)(out + q * 136u + 8u + f2 * 4u));
        }
        // ---- head stores: 8 c x 8 rows x 2 f4 = 128 f4 ----
        if (t < 128u) {
            unsigned c  = t >> 4;
            unsigned rr = (t >> 1) & 7u;
            unsigned h  = t & 1u;
            unsigned q  = (k * 8u + c) * 4096u + chunk * 16u + g * 8u + rr;
            f32x4 v = ((const f32x4*)x)[q * 2u + h];
            __builtin_nontemporal_store(v, (f32x4*)(out + q * 136u + h * 4u));
        }
        __syncthreads();   // sXT/sG reused by next group
    }
}

extern "C" void kernel_launch(void* const* d_in, const int* in_sizes, int n_in,
                              void* d_out, int out_size, void* d_ws, size_t ws_size,
                              hipStream_t stream) {
    const float* x     = (const float*)d_in[0];
    const float* scale = (const float*)d_in[1];
    const float* mean  = (const float*)d_in[2];
    float* out = (float*)d_out;

    const size_t NEED = (1024 + 16) * sizeof(float);
    if (ws_size >= NEED) {
        float* minv = (float*)d_ws;
        float* base = minv + 1024;
        prep_kernel<<<1, 64, 0, stream>>>(scale, minv, base);
        fused_kernel<false><<<4096, 256, 0, stream>>>(x, minv, base, mean, scale, out);
    } else {
        fused_kernel<true><<<4096, 256, 0, stream>>>(x, nullptr, nullptr, mean, scale, out);
    }
}

// Round 4
// 314.605 us; speedup vs baseline: 1.1453x; 1.1453x over previous
//
#include <hip/hip_runtime.h>

// Problem constants: B=8, H=256, W=256, C=8, K=16
// S = B*H*W = 524288 source pixels; out pixel q has 136 channels:
//   ch 0..7 = x[q][ch]
//   ch 8+j  = gauss[k][rem] * x[rem][c],  kc = q>>12 (k=kc>>3, c=kc&7),
//             rem = (q&4095)*128 + j   (j = 0..127)
//
// Two-pass design:
//   pass1: compute gauss[16][S] (each gaussian ONCE) + xT[8][S] into ws.
//   pass2: block b writes out slab of 128 consecutive rows (69.6 KB,
//          monotone block<->offset like the harness fill, which sustains
//          6.4 TB/s pure-write). All reads are contiguous f4 streams from
//          L2/L3-resident ws.
#define S_TOTAL 524288u
#define NEG4LOG2PI (-7.3515082656373808f)

typedef float f32x4 __attribute__((ext_vector_type(4)));

// ---------------- prep: invert lower-triangular L_k, compute base_k ----------------
__global__ void prep_kernel(const float* __restrict__ scale,
                            float* __restrict__ minv,
                            float* __restrict__ base) {
    int k = threadIdx.x;
    if (k >= 16) return;
    float L[8][8], M[8][8];
    const float* Ls = scale + k * 64;
    for (int i = 0; i < 8; i++)
        for (int j = 0; j < 8; j++) { L[i][j] = Ls[i * 8 + j]; M[i][j] = 0.f; }
    for (int j = 0; j < 8; j++) {
        M[j][j] = 1.0f / L[j][j];
        for (int i = j + 1; i < 8; i++) {
            float s = 0.f;
            for (int m = j; m < i; m++) s += L[i][m] * M[m][j];
            M[i][j] = -s / L[i][i];
        }
    }
    float logdet = 0.f;
    for (int i = 0; i < 8; i++) logdet += logf(fabsf(L[i][i]));
    for (int i = 0; i < 8; i++)
        for (int j = 0; j < 8; j++) minv[k * 64 + i * 8 + j] = M[i][j];
    base[k] = -logdet + NEG4LOG2PI;
}

// ---------------- pass1: gauss (once per (k,pixel)) + transposed x ----------------
// grid 2048 x 256, 1 pixel/thread. All loads/stores wave-coalesced.
// Plain stores (not nt): ws should stay L2/L3-resident for pass2.
__global__ __launch_bounds__(256) void gauss_xt_kernel(
    const float* __restrict__ x,
    const float* __restrict__ minv,
    const float* __restrict__ base,
    const float* __restrict__ mean,
    float* __restrict__ gauss,
    float* __restrict__ xt)
{
    __shared__ float sM[1024];   // 16 x 8x8
    __shared__ float sMu[128];   // 16 x 8
    __shared__ float sB[16];
    for (int i = threadIdx.x; i < 1024; i += 256) sM[i] = minv[i];
    if (threadIdx.x < 128) sMu[threadIdx.x] = mean[threadIdx.x];
    if (threadIdx.x < 16)  sB[threadIdx.x] = base[threadIdx.x];
    __syncthreads();

    unsigned s = blockIdx.x * 256u + threadIdx.x;
    f32x4 a = ((const f32x4*)x)[s * 2u];
    f32x4 b = ((const f32x4*)x)[s * 2u + 1u];
    float xv[8] = {a.x, a.y, a.z, a.w, b.x, b.y, b.z, b.w};

    #pragma unroll
    for (int c = 0; c < 8; c++) xt[c * S_TOTAL + s] = xv[c];

    #pragma unroll
    for (int k = 0; k < 16; k++) {
        const float* M  = &sM[k * 64];
        const float* mu = &sMu[k * 8];
        float d[8];
        #pragma unroll
        for (int c = 0; c < 8; c++) d[c] = xv[c] - mu[c];
        float quad = 0.f;
        #pragma unroll
        for (int i = 0; i < 8; i++) {
            float y = 0.f;
            #pragma unroll
            for (int j = 0; j <= i; j++) y = fmaf(M[i * 8 + j], d[j], y);
            quad = fmaf(y, y, quad);
        }
        gauss[k * S_TOTAL + s] = __expf(fmaf(-0.5f, quad, sB[k]));
    }
}

// ---------------- pass2: monotone streaming out-sweep ----------------
// grid 4096 x 256. Block b owns 128 consecutive out rows (one kc):
//   kc = b>>5, rows q = kc*4096 + (b&31)*128 + r, r = 0..127.
// 128 rows x 34 f4 = 4352 f4 = 17 exact passes of 256 threads, stored in
// strictly ascending address order (like the fill). Reads: gk/xc are
// contiguous f4 streams (L2: sharers of gk are blocks +/-32 -> same XCD).
__global__ __launch_bounds__(256) void out_sweep_kernel(
    const float* __restrict__ x,
    const float* __restrict__ gauss,
    const float* __restrict__ xt,
    float* __restrict__ out)
{
    const unsigned t   = threadIdx.x;
    const unsigned b   = blockIdx.x;          // 0..4095
    const unsigned kc  = b >> 5;              // 0..127
    const unsigned k   = kc >> 3, c = kc & 7u;
    const unsigned rb  = (b & 31u) * 128u;    // r0 base within this kc
    const unsigned q0  = kc * 4096u + rb;     // first out row

    const f32x4* __restrict__ gk = (const f32x4*)(gauss + (size_t)k * S_TOTAL) + rb * 32u;
    const f32x4* __restrict__ xc = (const f32x4*)(xt    + (size_t)c * S_TOTAL) + rb * 32u;
    const f32x4* __restrict__ xh = (const f32x4*)(x + (size_t)q0 * 8u);
    f32x4* __restrict__ o = (f32x4*)(out + (size_t)q0 * 136u);

    #pragma unroll
    for (unsigned pass = 0; pass < 17u; ++pass) {
        unsigned i   = pass * 256u + t;   // 0..4351
        unsigned r   = i / 34u;           // magic-mul
        unsigned ch4 = i - r * 34u;       // 0..33
        f32x4 v;
        if (ch4 < 2u) {
            v = xh[r * 2u + ch4];                       // head: x row verbatim
        } else {
            unsigned idx = r * 32u + (ch4 - 2u);        // 0..4095
            v = gk[idx] * xc[idx];                      // tail: gauss * x[.,c]
        }
        __builtin_nontemporal_store(v, o + i);          // ascending addresses
    }
}

// ---------------- fallback: round-2 fused kernel (no workspace needed) ----------------
__global__ __launch_bounds__(256) void fused_kernel(
    const float* __restrict__ x,
    const float* __restrict__ mean,
    const float* __restrict__ scale,
    float* __restrict__ out)
{
    __shared__ float sM[1024];
    __shared__ float sMu[128];
    __shared__ float sB[16];
    __shared__ float sXrT[8][128];
    __shared__ float sGT[16][128];
    __shared__ float sXq[128][8];

    const unsigned t  = threadIdx.x;
    const unsigned r0 = blockIdx.x;

    if (t < 16u) {
        float L[8][8], M[8][8];
        const float* Ls = scale + t * 64u;
        for (int i = 0; i < 8; i++)
            for (int j = 0; j < 8; j++) { L[i][j] = Ls[i * 8 + j]; M[i][j] = 0.f; }
        for (int j = 0; j < 8; j++) {
            M[j][j] = 1.0f / L[j][j];
            for (int i = j + 1; i < 8; i++) {
                float s = 0.f;
                for (int m = j; m < i; m++) s += L[i][m] * M[m][j];
                M[i][j] = -s / L[i][i];
            }
        }
        float logdet = 0.f;
        for (int i = 0; i < 8; i++) logdet += logf(fabsf(L[i][i]));
        for (int i = 0; i < 8; i++)
            for (int j = 0; j < 8; j++) sM[t * 64u + i * 8 + j] = M[i][j];
        sB[t] = -logdet + NEG4LOG2PI;
    }
    if (t < 128u) sMu[t] = mean[t];

    {
        f32x4 v = ((const f32x4*)x)[r0 * 256u + t];
        unsigned p = t >> 1, h = (t & 1u) * 4u;
        sXrT[h + 0][p] = v.x; sXrT[h + 1][p] = v.y;
        sXrT[h + 2][p] = v.z; sXrT[h + 3][p] = v.w;
    }
    {
        unsigned kc = t >> 1, h = t & 1u;
        f32x4 v = ((const f32x4*)x)[(kc * 4096u + r0) * 2u + h];
        unsigned bofs = h * 4u;
        sXq[kc][bofs + 0] = v.x; sXq[kc][bofs + 1] = v.y;
        sXq[kc][bofs + 2] = v.z; sXq[kc][bofs + 3] = v.w;
    }
    __syncthreads();

    {
        unsigned j  = t & 127u;
        unsigned k0 = (t >> 7) * 8u;
        float xv[8];
        #pragma unroll
        for (int c = 0; c < 8; c++) xv[c] = sXrT[c][j];
        #pragma unroll
        for (unsigned kk = 0; kk < 8u; kk++) {
            unsigned k = k0 + kk;
            const float* M  = &sM[k * 64u];
            const float* mu = &sMu[k * 8u];
            float d[8];
            #pragma unroll
            for (int c = 0; c < 8; c++) d[c] = xv[c] - mu[c];
            float quad = 0.f;
            #pragma unroll
            for (int i = 0; i < 8; i++) {
                float y = 0.f;
                #pragma unroll
                for (int jj = 0; jj <= i; jj++) y = fmaf(M[i * 8 + jj], d[jj], y);
                quad = fmaf(y, y, quad);
            }
            sGT[k][j] = __expf(fmaf(-0.5f, quad, sB[k]));
        }
    }
    __syncthreads();

    for (unsigned i = t; i < 4352u; i += 256u) {
        unsigned kc = i / 34u;
        unsigned f4 = i - kc * 34u;
        f32x4 v;
        if (f4 < 2u) {
            v = *(const f32x4*)&sXq[kc][f4 * 4u];
        } else {
            unsigned j0 = f4 * 4u - 8u;
            unsigned k  = kc >> 3, c = kc & 7u;
            f32x4 g  = *(const f32x4*)&sGT[k][j0];
            f32x4 xcv = *(const f32x4*)&sXrT[c][j0];
            v = g * xcv;
        }
        float* dst = out + (kc * 4096u + r0) * 136u + f4 * 4u;
        __builtin_nontemporal_store(v, (f32x4*)dst);
    }
}

extern "C" void kernel_launch(void* const* d_in, const int* in_sizes, int n_in,
                              void* d_out, int out_size, void* d_ws, size_t ws_size,
                              hipStream_t stream) {
    const float* x     = (const float*)d_in[0];
    const float* scale = (const float*)d_in[1];
    const float* mean  = (const float*)d_in[2];
    float* out = (float*)d_out;

    const size_t GAUSS_BYTES = (size_t)16 * S_TOTAL * 4;   // 33.55 MB
    const size_t XT_BYTES    = (size_t)8  * S_TOTAL * 4;   // 16.78 MB
    const size_t NEED = GAUSS_BYTES + XT_BYTES + (1024 + 16) * sizeof(float);

    if (ws_size >= NEED) {
        float* gauss = (float*)d_ws;
        float* xt    = (float*)((char*)d_ws + GAUSS_BYTES);
        float* minv  = (float*)((char*)d_ws + GAUSS_BYTES + XT_BYTES);
        float* base  = minv + 1024;
        prep_kernel<<<1, 64, 0, stream>>>(scale, minv, base);
        gauss_xt_kernel<<<S_TOTAL / 256, 256, 0, stream>>>(x, minv, base, mean, gauss, xt);
        out_sweep_kernel<<<4096, 256, 0, stream>>>(x, gauss, xt, out);
    } else {
        fused_kernel<<<4096, 256, 0, stream>>>(x, mean, scale, out);
    }
}